// Round 12
// baseline (2591.518 us; speedup 1.0000x reference)
//
#include <hip/hip_runtime.h>
#include <math.h>

#define BB 4
#define NN 8192
#define SS 2048
#define KK 32
#define NGR 8

// ---------------- prep: per-point squared norm (strict rounding) ----------------
__global__ void k_sqn(const float* __restrict__ xyz, float* __restrict__ sqn) {
  int i = blockIdx.x * 256 + threadIdx.x;
  if (i >= BB * NN) return;
  int b = i >> 13, n = i & (NN - 1);
  const float* p = xyz + (size_t)b * 3 * NN;
  float x = p[n], y = p[NN + n], z = p[2 * NN + n];
  sqn[i] = __fadd_rn(__fadd_rn(__fmul_rn(x, x), __fmul_rn(y, y)), __fmul_rn(z, z));
}

// ---------------- prep: transpose points (B,64,N) -> (B,N,64) ----------------
__global__ void k_tr(const float* __restrict__ pts, float* __restrict__ ptst) {
  __shared__ float tile[64][65];
  int b = blockIdx.y;
  int n0 = blockIdx.x * 64;
  int t = threadIdx.x;
  {
    int n = t & 63, cq = t >> 6;
    for (int j = 0; j < 16; ++j) {
      int c = cq * 16 + j;
      tile[c][n] = pts[((size_t)b * 64 + c) * NN + n0 + n];
    }
  }
  __syncthreads();
  {
    int c = t & 63, nq = t >> 6;
    for (int j = 0; j < 16; ++j) {
      int nn2 = nq * 16 + j;
      ptst[((size_t)b * NN + n0 + nn2) * 64 + c] = tile[c][nn2];
    }
  }
}

// ---------------- prep: generic small weight transpose ----------------
__global__ void k_wt(const float* __restrict__ src, float* __restrict__ dst, int rows, int cols) {
  int i = blockIdx.x * 256 + threadIdx.x;
  if (i >= rows * cols) return;
  int r = i / cols, c = i - r * cols;
  dst[c * rows + r] = src[i];
}

// ---------------- prep: modulation (scale/shift from t_emb/c_emb) ----------------
__global__ void k_mod(const float* __restrict__ te, const float* __restrict__ ce,
                      const float* __restrict__ wt, const float* __restrict__ bt,
                      const float* __restrict__ wc, const float* __restrict__ bc,
                      float* __restrict__ scl, float* __restrict__ shf) {
  int t = blockIdx.x * 256 + threadIdx.x;
  if (t >= BB * 128) return;
  int b = t >> 7, o = t & 127;
  const float* tb = te + b * 128;
  const float* cb = ce + b * 128;
  float s1 = 0.f, s2 = 0.f, h1 = 0.f, h2 = 0.f;
  for (int c = 0; c < 128; ++c) {
    float tv = tb[c], cv = cb[c];
    s1 = fmaf(tv, wt[o * 128 + c], s1);
    h1 = fmaf(tv, wt[(o + 128) * 128 + c], h1);
    s2 = fmaf(cv, wc[o * 128 + c], s2);
    h2 = fmaf(cv, wc[(o + 128) * 128 + c], h2);
  }
  scl[t] = s1 + bt[o] + s2 + bc[o];
  shf[t] = h1 + bt[o + 128] + h2 + bc[o + 128];
}

// ---------------- FPS: 1 block (1024 thr) per batch, register-pinned points ----------------
// Round-11: pinning removed the in-loop reload (FETCH flat, -13%), but iter is
// still 2300cyc @ ~80% per-CU VALUBusy => either extra VALU overhead (issue-
// bound) or a latency tail 2 waves/SIMD can't hide. Round-12 test: 1024 thr
// (FPT=8, 4 waves/SIMD) — per-SIMD update issue is invariant, latency hiding
// doubles. Lane-parallel block merge (ds_read wk[t&15] + 4 DPP steps) keeps
// the duplicated per-wave overhead small.
// key = (f32 bits of dist << 32) | (NN-1-idx); u64 max == (max dist, min idx).
template <int CTRL>
__device__ __forceinline__ unsigned long long kmax_dpp(unsigned long long key) {
  int lo = (int)(unsigned)(key & 0xffffffffull);
  int hi = (int)(unsigned)(key >> 32);
  int olo = __builtin_amdgcn_update_dpp(lo, lo, CTRL, 0xf, 0xf, false);
  int ohi = __builtin_amdgcn_update_dpp(hi, hi, CTRL, 0xf, 0xf, false);
  unsigned long long other =
      ((unsigned long long)(unsigned)ohi << 32) | (unsigned)olo;
  return other > key ? other : key;
}

#define FT 1024
#define FPT (NN / FT)  // 8 points per thread
#define FW (FT / 64)   // 16 waves

__global__ __launch_bounds__(FT, 1) void k_fps(const float* __restrict__ xyz,
                                               float* __restrict__ newxyz) {
  int b = blockIdx.x;
  int t = threadIdx.x;
  const float* gx = xyz + (size_t)b * 3 * NN;
  const float* gy = gx + NN;
  const float* gz = gx + 2 * NN;
  __shared__ float4 p4[NN];                      // centroid-broadcast store only
  __shared__ unsigned long long wk[2][FW];       // parity-double-buffered wave keys
  for (int i = t; i < NN; i += FT)
    p4[i] = make_float4(gx[i], gy[i], gz[i], 0.f);
  float px[FPT], py[FPT], pz[FPT], dm[FPT];
#pragma unroll
  for (int j = 0; j < FPT; ++j) {
    px[j] = gx[t + j * FT];
    py[j] = gy[t + j * FT];
    pz[j] = gz[t + j * FT];
    dm[j] = 1e10f;
    // pin in VGPRs: asm "writes" these, so the loads can't be sunk into the loop
    asm volatile("" : "+v"(px[j]), "+v"(py[j]), "+v"(pz[j]));
  }
  __syncthreads();
  int far = 0;
  float* ox = newxyz + (size_t)b * 3 * SS;
  for (int k = 0; k < SS; ++k) {
    float4 c = p4[far];  // uniform addr -> LDS broadcast (no global in chain)
    if (t == 0) { ox[k] = c.x; ox[SS + k] = c.y; ox[2 * SS + k] = c.z; }
    float bv = -1.f;
    int jb = 0;
#pragma unroll
    for (int j = 0; j < FPT; ++j) {
      float dx = __fsub_rn(px[j], c.x);
      float dy = __fsub_rn(py[j], c.y);
      float dz = __fsub_rn(pz[j], c.z);
      float d = __fadd_rn(__fadd_rn(__fmul_rn(dx, dx), __fmul_rn(dy, dy)), __fmul_rn(dz, dz));
      float m = fminf(dm[j], d);
      dm[j] = m;
      if (m > bv) { bv = m; jb = j; }  // strict >; j is an inline const
    }
    int bp = t + jb * FT;
    unsigned long long key =
        ((unsigned long long)__float_as_uint(bv) << 32) | (unsigned)(NN - 1 - bp);
    key = kmax_dpp<0xB1>(key);   // xor 1
    key = kmax_dpp<0x4E>(key);   // xor 2
    key = kmax_dpp<0x141>(key);  // half_mirror: pairs across 4-groups
    key = kmax_dpp<0x140>(key);  // mirror: pairs across 8-groups -> row max
    key = kmax_dpp<0x142>(key);  // bcast15: row1=max(r0,r1), row3=max(r2,r3)
    key = kmax_dpp<0x143>(key);  // bcast31: rows2-3 = full wave max (lane 63)
    if ((t & 63) == 63) wk[k & 1][t >> 6] = key;
    __syncthreads();
    // lane-parallel merge: each lane reads one of the 16 wave keys, 4 DPP
    // steps reduce across the 16-lane row; all lanes converge to the max.
    unsigned long long kg = wk[k & 1][t & (FW - 1)];
    kg = kmax_dpp<0xB1>(kg);   // xor 1
    kg = kmax_dpp<0x4E>(kg);   // xor 2
    kg = kmax_dpp<0x141>(kg);  // half_mirror
    kg = kmax_dpp<0x140>(kg);  // mirror -> max over 16 keys
    far = NN - 1 - (int)(unsigned)(kg & 0xffffffffull);
    far = __builtin_amdgcn_readfirstlane(far);
  }
}

// ---------------- ball query: 1 wave per center, ordered scan + ballot compact ----------------
__global__ __launch_bounds__(256) void k_ballq(const float* __restrict__ xyz,
                                               const float* __restrict__ sqn,
                                               const float* __restrict__ newxyz,
                                               int* __restrict__ gi) {
  int wid = (blockIdx.x * 256 + threadIdx.x) >> 6;
  int lane = threadIdx.x & 63;
  if (wid >= BB * SS) return;
  int b = wid >> 11, s = wid & (SS - 1);
  const float* nx = newxyz + (size_t)b * 3 * SS;
  float sx = nx[s], sy = nx[SS + s], sz = nx[2 * SS + s];
  float ss = __fadd_rn(__fadd_rn(__fmul_rn(sx, sx), __fmul_rn(sy, sy)), __fmul_rn(sz, sz));
  const float* gx = xyz + (size_t)b * 3 * NN;
  const float* gy = gx + NN;
  const float* gz = gx + 2 * NN;
  const float* sn = sqn + (size_t)b * NN;
  int* go = gi + (size_t)wid * KK;
  int found = 0, first = 0;
  for (int n0 = 0; n0 < NN && found < KK; n0 += 64) {
    int n = n0 + lane;
    float x = gx[n], y = gy[n], z = gz[n];
    float ip = __fmul_rn(sx, x);
    ip = __fmaf_rn(sy, y, ip);
    ip = __fmaf_rn(sz, z, ip);
    float d = __fsub_rn(__fadd_rn(ss, sn[n]), __fmul_rn(2.0f, ip));
    bool pred = (d <= 0.25f);
    unsigned long long m = __ballot(pred);
    if (found == 0 && m) first = n0 + __ffsll((unsigned long long)m) - 1;
    if (pred) {
      int pos = found + __popcll(m & ((1ull << lane) - 1ull));
      if (pos < KK) go[pos] = n;
    }
    found += __popcll(m);
  }
  for (int p = found + lane; p < KK; p += 64) go[p] = first;
}

// ---------------- MLP0 (gather + W0*feat), PASS 0: stats, PASS 1: norm+silu+maxpool ----------------
template <int PASS>
__global__ __launch_bounds__(256) void k_mlp0(
    const float* __restrict__ xyz, const float* __restrict__ ptst,
    const float* __restrict__ newxyz, const int* __restrict__ gi,
    const float* __restrict__ w0, const float* __restrict__ b0,
    double* __restrict__ dst, const float* __restrict__ fmu, const float* __restrict__ frs,
    const float* __restrict__ g0, const float* __restrict__ be0,
    float* __restrict__ xp) {
  __shared__ __align__(16) float w0L[128 * 67];
  __shared__ __align__(16) float featL[67 * 36];
  __shared__ int giL[KK];
  __shared__ float sS[NGR], sQ[NGR];
  __shared__ float maxL[128];
  int t = threadIdx.x;
  int bs = blockIdx.x;
  int b = bs >> 11;
  int s = bs & (SS - 1);
  for (int i = t; i < 128 * 67; i += 256) w0L[i] = w0[i];
  if (t < KK) giL[t] = gi[(size_t)bs * KK + t];
  if (PASS == 0 && t < NGR) { sS[t] = 0.f; sQ[t] = 0.f; }
  __syncthreads();
  {
    int k = t & 31, q = t >> 5;
    int idx = giL[k];
    const float4* src = (const float4*)(ptst + ((size_t)b * NN + idx) * 64 + q * 8);
    float4 v0 = src[0], v1 = src[1];
    int cb = 3 + q * 8;
    featL[(cb + 0) * 36 + k] = v0.x;
    featL[(cb + 1) * 36 + k] = v0.y;
    featL[(cb + 2) * 36 + k] = v0.z;
    featL[(cb + 3) * 36 + k] = v0.w;
    featL[(cb + 4) * 36 + k] = v1.x;
    featL[(cb + 5) * 36 + k] = v1.y;
    featL[(cb + 6) * 36 + k] = v1.z;
    featL[(cb + 7) * 36 + k] = v1.w;
    if (q == 0) {
      const float* gx = xyz + (size_t)b * 3 * NN;
      const float* nx = newxyz + (size_t)b * 3 * SS;
      featL[0 * 36 + k] = gx[idx] - nx[s];
      featL[1 * 36 + k] = gx[NN + idx] - nx[SS + s];
      featL[2 * 36 + k] = gx[2 * NN + idx] - nx[2 * SS + s];
    }
  }
  __syncthreads();
  int o = t & 127, kh = t >> 7;
  float acc[16];
#pragma unroll
  for (int j = 0; j < 16; ++j) acc[j] = 0.f;
  const float* wrow = w0L + o * 67;
  const float* fb = featL + kh * 16;
  for (int c = 0; c < 67; ++c) {
    float w = wrow[c];
    const float4* f4 = (const float4*)(fb + c * 36);
    float4 a = f4[0], b4 = f4[1], c4 = f4[2], d4 = f4[3];
    acc[0] = fmaf(w, a.x, acc[0]);    acc[1] = fmaf(w, a.y, acc[1]);
    acc[2] = fmaf(w, a.z, acc[2]);    acc[3] = fmaf(w, a.w, acc[3]);
    acc[4] = fmaf(w, b4.x, acc[4]);   acc[5] = fmaf(w, b4.y, acc[5]);
    acc[6] = fmaf(w, b4.z, acc[6]);   acc[7] = fmaf(w, b4.w, acc[7]);
    acc[8] = fmaf(w, c4.x, acc[8]);   acc[9] = fmaf(w, c4.y, acc[9]);
    acc[10] = fmaf(w, c4.z, acc[10]); acc[11] = fmaf(w, c4.w, acc[11]);
    acc[12] = fmaf(w, d4.x, acc[12]); acc[13] = fmaf(w, d4.y, acc[13]);
    acc[14] = fmaf(w, d4.z, acc[14]); acc[15] = fmaf(w, d4.w, acc[15]);
  }
  float bb = b0[o];
  int g = o >> 4;
  if (PASS == 0) {
    float ps = 0.f, pq = 0.f;
#pragma unroll
    for (int j = 0; j < 16; ++j) { float v = acc[j] + bb; ps += v; pq += v * v; }
    atomicAdd(&sS[g], ps);
    atomicAdd(&sQ[g], pq);
    __syncthreads();
    if (t < NGR) {
      atomicAdd(&dst[b * NGR + t], (double)sS[t]);
      atomicAdd(&dst[32 + b * NGR + t], (double)sQ[t]);
    }
  } else {
    float mu = fmu[b * NGR + g], rs = frs[b * NGR + g];
    float ga = g0[o], be = be0[o];
    float m = -3.4e38f;
#pragma unroll
    for (int j = 0; j < 16; ++j) {
      float v = acc[j] + bb;
      v = (v - mu) * rs * ga + be;
      v = v / (1.f + expf(-v));
      m = fmaxf(m, v);
    }
    if (kh == 0) maxL[o] = m;
    __syncthreads();
    if (kh == 1) xp[(size_t)bs * 128 + o] = fmaxf(maxL[o], m);
  }
}

// ---------------- finalize group stats: mu, rsqrt(var+eps) ----------------
__global__ void k_fin(const double* __restrict__ dst, float* __restrict__ fmu,
                      float* __restrict__ frs, double cntInv) {
  int i = threadIdx.x;
  if (i >= BB * NGR) return;
  double m = dst[i] * cntInv;
  double q = dst[32 + i] * cntInv;
  double var = q - m * m;
  fmu[i] = (float)m;
  frs[i] = (float)rsqrt(var + 1e-5);
}

// ---------------- MLP1: h1 = w1 @ xp + b1, accumulate gn1 stats ----------------
__global__ __launch_bounds__(256) void k_mlp1(
    const float* __restrict__ xp, const float* __restrict__ w1t,
    const float* __restrict__ b1, float* __restrict__ h1, double* __restrict__ dst) {
  __shared__ __align__(16) float xpL[8 * 128];
  __shared__ float sS[NGR], sQ[NGR];
  int t = threadIdx.x;
  int bs0 = blockIdx.x * 8;
  int b = bs0 >> 11;
  if (t < NGR) { sS[t] = 0.f; sQ[t] = 0.f; }
  {
    int idx4 = t >> 5, l = t & 31;
    ((float4*)xpL)[idx4 * 32 + l] = ((const float4*)(xp + (size_t)bs0 * 128))[idx4 * 32 + l];
  }
  __syncthreads();
  float acc0[8], acc1[8];
#pragma unroll
  for (int i = 0; i < 8; ++i) { acc0[i] = 0.f; acc1[i] = 0.f; }
  for (int c4 = 0; c4 < 32; ++c4) {
    float wa0 = w1t[(c4 * 4 + 0) * 512 + t];
    float wa1 = w1t[(c4 * 4 + 1) * 512 + t];
    float wa2 = w1t[(c4 * 4 + 2) * 512 + t];
    float wa3 = w1t[(c4 * 4 + 3) * 512 + t];
    float wb0 = w1t[(c4 * 4 + 0) * 512 + 256 + t];
    float wb1 = w1t[(c4 * 4 + 1) * 512 + 256 + t];
    float wb2 = w1t[(c4 * 4 + 2) * 512 + 256 + t];
    float wb3 = w1t[(c4 * 4 + 3) * 512 + 256 + t];
#pragma unroll
    for (int si = 0; si < 8; ++si) {
      float4 xv = *(const float4*)(xpL + si * 128 + c4 * 4);
      acc0[si] = fmaf(wa0, xv.x, acc0[si]);
      acc0[si] = fmaf(wa1, xv.y, acc0[si]);
      acc0[si] = fmaf(wa2, xv.z, acc0[si]);
      acc0[si] = fmaf(wa3, xv.w, acc0[si]);
      acc1[si] = fmaf(wb0, xv.x, acc1[si]);
      acc1[si] = fmaf(wb1, xv.y, acc1[si]);
      acc1[si] = fmaf(wb2, xv.z, acc1[si]);
      acc1[si] = fmaf(wb3, xv.w, acc1[si]);
    }
  }
  float ba = b1[t], bbv = b1[256 + t];
  float ps0 = 0.f, pq0 = 0.f, ps1 = 0.f, pq1 = 0.f;
#pragma unroll
  for (int si = 0; si < 8; ++si) {
    float va = acc0[si] + ba;
    float vb = acc1[si] + bbv;
    h1[(size_t)(bs0 + si) * 512 + t] = va;
    h1[(size_t)(bs0 + si) * 512 + 256 + t] = vb;
    ps0 += va; pq0 += va * va;
    ps1 += vb; pq1 += vb * vb;
  }
  atomicAdd(&sS[t >> 6], ps0);
  atomicAdd(&sQ[t >> 6], pq0);
  atomicAdd(&sS[4 + (t >> 6)], ps1);
  atomicAdd(&sQ[4 + (t >> 6)], pq1);
  __syncthreads();
  if (t < NGR) {
    atomicAdd(&dst[b * NGR + t], (double)sS[t]);
    atomicAdd(&dst[32 + b * NGR + t], (double)sQ[t]);
  }
}

// ---------------- MLP2: h2 = w2 @ silu(gn1(h1)) + b2, accumulate gn2 stats ----------------
__global__ __launch_bounds__(256) void k_mlp2(
    const float* __restrict__ h1, const float* __restrict__ w2t,
    const float* __restrict__ b2, const float* __restrict__ fmu1, const float* __restrict__ frs1,
    const float* __restrict__ g1, const float* __restrict__ be1,
    float* __restrict__ h2, double* __restrict__ dst) {
  __shared__ __align__(16) float hL[8 * 512];
  __shared__ float sS[NGR], sQ[NGR];
  int t = threadIdx.x;
  int bs0 = blockIdx.x * 8;
  int b = bs0 >> 11;
  if (t < NGR) { sS[t] = 0.f; sQ[t] = 0.f; }
  {
    int si = t >> 5, l = t & 31;
    int c0 = l * 16;
    int g = c0 >> 6;
    float mu = fmu1[b * NGR + g], rs = frs1[b * NGR + g];
    const float* src = h1 + (size_t)(bs0 + si) * 512 + c0;
#pragma unroll
    for (int j = 0; j < 16; ++j) {
      float v = src[j];
      v = (v - mu) * rs * g1[c0 + j] + be1[c0 + j];
      v = v / (1.f + expf(-v));
      hL[si * 512 + c0 + j] = v;
    }
  }
  __syncthreads();
  int o = t & 127, sh = t >> 7;
  float acc[4] = {0.f, 0.f, 0.f, 0.f};
  for (int c4 = 0; c4 < 128; ++c4) {
    float w0v = w2t[(c4 * 4 + 0) * 128 + o];
    float w1v = w2t[(c4 * 4 + 1) * 128 + o];
    float w2v = w2t[(c4 * 4 + 2) * 128 + o];
    float w3v = w2t[(c4 * 4 + 3) * 128 + o];
#pragma unroll
    for (int m = 0; m < 4; ++m) {
      float4 hq = *(const float4*)(hL + (sh * 4 + m) * 512 + c4 * 4);
      acc[m] = fmaf(w0v, hq.x, acc[m]);
      acc[m] = fmaf(w1v, hq.y, acc[m]);
      acc[m] = fmaf(w2v, hq.z, acc[m]);
      acc[m] = fmaf(w3v, hq.w, acc[m]);
    }
  }
  float bb = b2[o];
  float ps = 0.f, pq = 0.f;
#pragma unroll
  for (int m = 0; m < 4; ++m) {
    float v = acc[m] + bb;
    h2[(size_t)(bs0 + sh * 4 + m) * 128 + o] = v;
    ps += v; pq += v * v;
  }
  atomicAdd(&sS[o >> 4], ps);
  atomicAdd(&sQ[o >> 4], pq);
  __syncthreads();
  if (t < NGR) {
    atomicAdd(&dst[b * NGR + t], (double)sS[t]);
    atomicAdd(&dst[32 + b * NGR + t], (double)sQ[t]);
  }
}

// ---------------- final: gn2 + modulation + residual ----------------
__global__ void k_final(const float* __restrict__ h2, const float* __restrict__ xp,
                        const float* __restrict__ fmu2, const float* __restrict__ frs2,
                        const float* __restrict__ g2, const float* __restrict__ be2,
                        const float* __restrict__ scl, const float* __restrict__ shf,
                        float* __restrict__ out) {
  int f = blockIdx.x * 256 + threadIdx.x;
  if (f >= BB * 128 * SS) return;
  int s = f & (SS - 1);
  int o = (f >> 11) & 127;
  int b = f >> 18;
  int g = o >> 4;
  float v = h2[((size_t)b * SS + s) * 128 + o];
  v = (v - fmu2[b * NGR + g]) * frs2[b * NGR + g] * g2[o] + be2[o];
  float idv = xp[((size_t)b * SS + s) * 128 + o];
  out[f] = v * (1.f + scl[b * 128 + o]) + shf[b * 128 + o] + idv;
}

extern "C" void kernel_launch(void* const* d_in, const int* in_sizes, int n_in,
                              void* d_out, int out_size, void* d_ws, size_t ws_size,
                              hipStream_t stream) {
  const float* xyz = (const float*)d_in[0];
  const float* pts = (const float*)d_in[1];
  const float* te = (const float*)d_in[2];
  const float* ce = (const float*)d_in[3];
  const float* w0 = (const float*)d_in[4];
  const float* b0 = (const float*)d_in[5];
  const float* g0 = (const float*)d_in[6];
  const float* be0 = (const float*)d_in[7];
  const float* w1 = (const float*)d_in[8];
  const float* b1 = (const float*)d_in[9];
  const float* g1 = (const float*)d_in[10];
  const float* be1 = (const float*)d_in[11];
  const float* w2 = (const float*)d_in[12];
  const float* b2 = (const float*)d_in[13];
  const float* g2 = (const float*)d_in[14];
  const float* be2 = (const float*)d_in[15];
  const float* wt = (const float*)d_in[16];
  const float* bt = (const float*)d_in[17];
  const float* wc = (const float*)d_in[18];
  const float* bc = (const float*)d_in[19];

  char* ws = (char*)d_ws;
  size_t off = 0;
  auto alloc = [&](size_t bytes) {
    void* p = ws + off;
    off += (bytes + 255) & ~(size_t)255;
    return p;
  };
  float* ptst = (float*)alloc((size_t)BB * NN * 64 * 4);
  float* sqn = (float*)alloc((size_t)BB * NN * 4);
  int* gi = (int*)alloc((size_t)BB * SS * KK * 4);
  float* xp = (float*)alloc((size_t)BB * SS * 128 * 4);
  float* h1 = (float*)alloc((size_t)BB * SS * 512 * 4);
  float* h2 = (float*)alloc((size_t)BB * SS * 128 * 4);
  float* w1t = (float*)alloc(512 * 128 * 4);
  float* w2t = (float*)alloc(512 * 128 * 4);
  float* scl = (float*)alloc(BB * 128 * 4);
  float* shf = (float*)alloc(BB * 128 * 4);
  double* dstat = (double*)alloc(3 * 64 * 8);
  float* fmu = (float*)alloc(3 * 32 * 4);
  float* frs = (float*)alloc(3 * 32 * 4);

  float* newxyz = (float*)d_out;
  float* outnp = (float*)d_out + (size_t)BB * 3 * SS;

  hipMemsetAsync(dstat, 0, 3 * 64 * 8, stream);
  k_sqn<<<BB * NN / 256, 256, 0, stream>>>(xyz, sqn);
  k_tr<<<dim3(NN / 64, BB), 256, 0, stream>>>(pts, ptst);
  k_wt<<<(512 * 128 + 255) / 256, 256, 0, stream>>>(w1, w1t, 512, 128);
  k_wt<<<(512 * 128 + 255) / 256, 256, 0, stream>>>(w2, w2t, 128, 512);
  k_mod<<<2, 256, 0, stream>>>(te, ce, wt, bt, wc, bc, scl, shf);
  k_fps<<<BB, FT, 0, stream>>>(xyz, newxyz);
  k_ballq<<<BB * SS / 4, 256, 0, stream>>>(xyz, sqn, newxyz, gi);
  k_mlp0<0><<<BB * SS, 256, 0, stream>>>(xyz, ptst, newxyz, gi, w0, b0, dstat, fmu, frs, g0, be0, xp);
  k_fin<<<1, 64, 0, stream>>>(dstat, fmu, frs, 1.0 / (16.0 * SS * KK));
  k_mlp0<1><<<BB * SS, 256, 0, stream>>>(xyz, ptst, newxyz, gi, w0, b0, dstat, fmu, frs, g0, be0, xp);
  k_mlp1<<<BB * SS / 8, 256, 0, stream>>>(xp, w1t, b1, h1, dstat + 64);
  k_fin<<<1, 64, 0, stream>>>(dstat + 64, fmu + 32, frs + 32, 1.0 / (64.0 * SS));
  k_mlp2<<<BB * SS / 8, 256, 0, stream>>>(h1, w2t, b2, fmu + 32, frs + 32, g1, be1, h2, dstat + 128);
  k_fin<<<1, 64, 0, stream>>>(dstat + 128, fmu + 64, frs + 64, 1.0 / (16.0 * SS));
  k_final<<<BB * 128 * SS / 256, 256, 0, stream>>>(h2, xp, fmu + 64, frs + 64, g2, be2, scl, shf, outnp);
}

// Round 13
// 2328.651 us; speedup vs baseline: 1.1129x; 1.1129x over previous
//
#include <hip/hip_runtime.h>
#include <math.h>

#define BB 4
#define NN 8192
#define SS 2048
#define KK 32
#define NGR 8

// ---------------- prep: per-point squared norm (strict rounding) ----------------
__global__ void k_sqn(const float* __restrict__ xyz, float* __restrict__ sqn) {
  int i = blockIdx.x * 256 + threadIdx.x;
  if (i >= BB * NN) return;
  int b = i >> 13, n = i & (NN - 1);
  const float* p = xyz + (size_t)b * 3 * NN;
  float x = p[n], y = p[NN + n], z = p[2 * NN + n];
  sqn[i] = __fadd_rn(__fadd_rn(__fmul_rn(x, x), __fmul_rn(y, y)), __fmul_rn(z, z));
}

// ---------------- prep: transpose points (B,64,N) -> (B,N,64) ----------------
__global__ void k_tr(const float* __restrict__ pts, float* __restrict__ ptst) {
  __shared__ float tile[64][65];
  int b = blockIdx.y;
  int n0 = blockIdx.x * 64;
  int t = threadIdx.x;
  {
    int n = t & 63, cq = t >> 6;
    for (int j = 0; j < 16; ++j) {
      int c = cq * 16 + j;
      tile[c][n] = pts[((size_t)b * 64 + c) * NN + n0 + n];
    }
  }
  __syncthreads();
  {
    int c = t & 63, nq = t >> 6;
    for (int j = 0; j < 16; ++j) {
      int nn2 = nq * 16 + j;
      ptst[((size_t)b * NN + n0 + nn2) * 64 + c] = tile[c][nn2];
    }
  }
}

// ---------------- prep: generic small weight transpose ----------------
__global__ void k_wt(const float* __restrict__ src, float* __restrict__ dst, int rows, int cols) {
  int i = blockIdx.x * 256 + threadIdx.x;
  if (i >= rows * cols) return;
  int r = i / cols, c = i - r * cols;
  dst[c * rows + r] = src[i];
}

// ---------------- prep: modulation (scale/shift from t_emb/c_emb) ----------------
__global__ void k_mod(const float* __restrict__ te, const float* __restrict__ ce,
                      const float* __restrict__ wt, const float* __restrict__ bt,
                      const float* __restrict__ wc, const float* __restrict__ bc,
                      float* __restrict__ scl, float* __restrict__ shf) {
  int t = blockIdx.x * 256 + threadIdx.x;
  if (t >= BB * 128) return;
  int b = t >> 7, o = t & 127;
  const float* tb = te + b * 128;
  const float* cb = ce + b * 128;
  float s1 = 0.f, s2 = 0.f, h1 = 0.f, h2 = 0.f;
  for (int c = 0; c < 128; ++c) {
    float tv = tb[c], cv = cb[c];
    s1 = fmaf(tv, wt[o * 128 + c], s1);
    h1 = fmaf(tv, wt[(o + 128) * 128 + c], h1);
    s2 = fmaf(cv, wc[o * 128 + c], s2);
    h2 = fmaf(cv, wc[(o + 128) * 128 + c], h2);
  }
  scl[t] = s1 + bt[o] + s2 + bc[o];
  shf[t] = h1 + bt[o + 128] + h2 + bc[o + 128];
}

// ---------------- FPS: 1 block (512 thr) per batch, register-pinned points ----------------
// Round-12: FT=1024 regressed (per-wave overhead duplicated; ~99% per-CU
// VALUBusy = issue-bound). Revert to FT=512. Round-13 fix: the in-loop
// `if(t==0) ox[k]=...` global stores force wave0 to drain vmcnt(0) at EVERY
// barrier (~300-900cyc serial tail). Record far in LDS fars[] instead; loop
// is now global-free; newxyz written once at the end. Merge is lane-parallel
// (read wk[t&7] + 3 DPP steps) instead of 8 reads + 7 sequential u64 maxes.
// key = (f32 bits of dist << 32) | (NN-1-idx); u64 max == (max dist, min idx).
template <int CTRL>
__device__ __forceinline__ unsigned long long kmax_dpp(unsigned long long key) {
  int lo = (int)(unsigned)(key & 0xffffffffull);
  int hi = (int)(unsigned)(key >> 32);
  int olo = __builtin_amdgcn_update_dpp(lo, lo, CTRL, 0xf, 0xf, false);
  int ohi = __builtin_amdgcn_update_dpp(hi, hi, CTRL, 0xf, 0xf, false);
  unsigned long long other =
      ((unsigned long long)(unsigned)ohi << 32) | (unsigned)olo;
  return other > key ? other : key;
}

#define FT 512
#define FPT (NN / FT)  // 16 points per thread
#define FW (FT / 64)   // 8 waves

__global__ __launch_bounds__(FT, 1) void k_fps(const float* __restrict__ xyz,
                                               float* __restrict__ newxyz) {
  int b = blockIdx.x;
  int t = threadIdx.x;
  const float* gx = xyz + (size_t)b * 3 * NN;
  const float* gy = gx + NN;
  const float* gz = gx + 2 * NN;
  __shared__ float4 p4[NN];                      // 128 KB point store (centroid bcast)
  __shared__ unsigned long long wk[2][FW];       // parity-double-buffered wave keys
  __shared__ int fars[SS];                       // 8 KB chosen indices
  for (int i = t; i < NN; i += FT)
    p4[i] = make_float4(gx[i], gy[i], gz[i], 0.f);
  float px[FPT], py[FPT], pz[FPT], dm[FPT];
#pragma unroll
  for (int j = 0; j < FPT; ++j) {
    px[j] = gx[t + j * FT];
    py[j] = gy[t + j * FT];
    pz[j] = gz[t + j * FT];
    dm[j] = 1e10f;
    // pin in VGPRs: asm "writes" these, so the loads can't be sunk into the loop
    asm volatile("" : "+v"(px[j]), "+v"(py[j]), "+v"(pz[j]));
  }
  __syncthreads();
  int far = 0;
  for (int k = 0; k < SS; ++k) {
    float4 c = p4[far];            // uniform addr -> LDS broadcast
    if (t == 0) fars[k] = far;     // LDS only: no vmcnt drain at the barrier
    float bv = -1.f;
    int jb = 0;
#pragma unroll
    for (int j = 0; j < FPT; ++j) {
      float dx = __fsub_rn(px[j], c.x);
      float dy = __fsub_rn(py[j], c.y);
      float dz = __fsub_rn(pz[j], c.z);
      float d = __fadd_rn(__fadd_rn(__fmul_rn(dx, dx), __fmul_rn(dy, dy)), __fmul_rn(dz, dz));
      float m = fminf(dm[j], d);
      dm[j] = m;
      if (m > bv) { bv = m; jb = j; }  // strict >; j is an inline const
    }
    int bp = t + jb * FT;
    unsigned long long key =
        ((unsigned long long)__float_as_uint(bv) << 32) | (unsigned)(NN - 1 - bp);
    key = kmax_dpp<0xB1>(key);   // xor 1
    key = kmax_dpp<0x4E>(key);   // xor 2
    key = kmax_dpp<0x141>(key);  // half_mirror: pairs across 4-groups
    key = kmax_dpp<0x140>(key);  // mirror: pairs across 8-groups -> row max
    key = kmax_dpp<0x142>(key);  // bcast15: row1=max(r0,r1), row3=max(r2,r3)
    key = kmax_dpp<0x143>(key);  // bcast31: rows2-3 = full wave max (lane 63)
    if ((t & 63) == 63) wk[k & 1][t >> 6] = key;
    __syncthreads();
    // lane-parallel merge: each lane reads one of the 8 wave keys; 3 DPP
    // steps reduce within each 8-lane group -> every lane has the block max.
    unsigned long long kg = wk[k & 1][t & (FW - 1)];
    kg = kmax_dpp<0xB1>(kg);   // xor 1
    kg = kmax_dpp<0x4E>(kg);   // xor 2
    kg = kmax_dpp<0x141>(kg);  // half_mirror -> max over 8 keys
    far = NN - 1 - (int)(unsigned)(kg & 0xffffffffull);
    far = __builtin_amdgcn_readfirstlane(far);
  }
  __syncthreads();
  float* ox = newxyz + (size_t)b * 3 * SS;
  for (int k = t; k < SS; k += FT) {
    float4 c = p4[fars[k]];
    ox[k] = c.x; ox[SS + k] = c.y; ox[2 * SS + k] = c.z;
  }
}

// ---------------- ball query: 1 wave per center, ordered scan + ballot compact ----------------
__global__ __launch_bounds__(256) void k_ballq(const float* __restrict__ xyz,
                                               const float* __restrict__ sqn,
                                               const float* __restrict__ newxyz,
                                               int* __restrict__ gi) {
  int wid = (blockIdx.x * 256 + threadIdx.x) >> 6;
  int lane = threadIdx.x & 63;
  if (wid >= BB * SS) return;
  int b = wid >> 11, s = wid & (SS - 1);
  const float* nx = newxyz + (size_t)b * 3 * SS;
  float sx = nx[s], sy = nx[SS + s], sz = nx[2 * SS + s];
  float ss = __fadd_rn(__fadd_rn(__fmul_rn(sx, sx), __fmul_rn(sy, sy)), __fmul_rn(sz, sz));
  const float* gx = xyz + (size_t)b * 3 * NN;
  const float* gy = gx + NN;
  const float* gz = gx + 2 * NN;
  const float* sn = sqn + (size_t)b * NN;
  int* go = gi + (size_t)wid * KK;
  int found = 0, first = 0;
  for (int n0 = 0; n0 < NN && found < KK; n0 += 64) {
    int n = n0 + lane;
    float x = gx[n], y = gy[n], z = gz[n];
    float ip = __fmul_rn(sx, x);
    ip = __fmaf_rn(sy, y, ip);
    ip = __fmaf_rn(sz, z, ip);
    float d = __fsub_rn(__fadd_rn(ss, sn[n]), __fmul_rn(2.0f, ip));
    bool pred = (d <= 0.25f);
    unsigned long long m = __ballot(pred);
    if (found == 0 && m) first = n0 + __ffsll((unsigned long long)m) - 1;
    if (pred) {
      int pos = found + __popcll(m & ((1ull << lane) - 1ull));
      if (pos < KK) go[pos] = n;
    }
    found += __popcll(m);
  }
  for (int p = found + lane; p < KK; p += 64) go[p] = first;
}

// ---------------- MLP0 (gather + W0*feat), PASS 0: stats, PASS 1: norm+silu+maxpool ----------------
template <int PASS>
__global__ __launch_bounds__(256) void k_mlp0(
    const float* __restrict__ xyz, const float* __restrict__ ptst,
    const float* __restrict__ newxyz, const int* __restrict__ gi,
    const float* __restrict__ w0, const float* __restrict__ b0,
    double* __restrict__ dst, const float* __restrict__ fmu, const float* __restrict__ frs,
    const float* __restrict__ g0, const float* __restrict__ be0,
    float* __restrict__ xp) {
  __shared__ __align__(16) float w0L[128 * 67];
  __shared__ __align__(16) float featL[67 * 36];
  __shared__ int giL[KK];
  __shared__ float sS[NGR], sQ[NGR];
  __shared__ float maxL[128];
  int t = threadIdx.x;
  int bs = blockIdx.x;
  int b = bs >> 11;
  int s = bs & (SS - 1);
  for (int i = t; i < 128 * 67; i += 256) w0L[i] = w0[i];
  if (t < KK) giL[t] = gi[(size_t)bs * KK + t];
  if (PASS == 0 && t < NGR) { sS[t] = 0.f; sQ[t] = 0.f; }
  __syncthreads();
  {
    int k = t & 31, q = t >> 5;
    int idx = giL[k];
    const float4* src = (const float4*)(ptst + ((size_t)b * NN + idx) * 64 + q * 8);
    float4 v0 = src[0], v1 = src[1];
    int cb = 3 + q * 8;
    featL[(cb + 0) * 36 + k] = v0.x;
    featL[(cb + 1) * 36 + k] = v0.y;
    featL[(cb + 2) * 36 + k] = v0.z;
    featL[(cb + 3) * 36 + k] = v0.w;
    featL[(cb + 4) * 36 + k] = v1.x;
    featL[(cb + 5) * 36 + k] = v1.y;
    featL[(cb + 6) * 36 + k] = v1.z;
    featL[(cb + 7) * 36 + k] = v1.w;
    if (q == 0) {
      const float* gx = xyz + (size_t)b * 3 * NN;
      const float* nx = newxyz + (size_t)b * 3 * SS;
      featL[0 * 36 + k] = gx[idx] - nx[s];
      featL[1 * 36 + k] = gx[NN + idx] - nx[SS + s];
      featL[2 * 36 + k] = gx[2 * NN + idx] - nx[2 * SS + s];
    }
  }
  __syncthreads();
  int o = t & 127, kh = t >> 7;
  float acc[16];
#pragma unroll
  for (int j = 0; j < 16; ++j) acc[j] = 0.f;
  const float* wrow = w0L + o * 67;
  const float* fb = featL + kh * 16;
  for (int c = 0; c < 67; ++c) {
    float w = wrow[c];
    const float4* f4 = (const float4*)(fb + c * 36);
    float4 a = f4[0], b4 = f4[1], c4 = f4[2], d4 = f4[3];
    acc[0] = fmaf(w, a.x, acc[0]);    acc[1] = fmaf(w, a.y, acc[1]);
    acc[2] = fmaf(w, a.z, acc[2]);    acc[3] = fmaf(w, a.w, acc[3]);
    acc[4] = fmaf(w, b4.x, acc[4]);   acc[5] = fmaf(w, b4.y, acc[5]);
    acc[6] = fmaf(w, b4.z, acc[6]);   acc[7] = fmaf(w, b4.w, acc[7]);
    acc[8] = fmaf(w, c4.x, acc[8]);   acc[9] = fmaf(w, c4.y, acc[9]);
    acc[10] = fmaf(w, c4.z, acc[10]); acc[11] = fmaf(w, c4.w, acc[11]);
    acc[12] = fmaf(w, d4.x, acc[12]); acc[13] = fmaf(w, d4.y, acc[13]);
    acc[14] = fmaf(w, d4.z, acc[14]); acc[15] = fmaf(w, d4.w, acc[15]);
  }
  float bb = b0[o];
  int g = o >> 4;
  if (PASS == 0) {
    float ps = 0.f, pq = 0.f;
#pragma unroll
    for (int j = 0; j < 16; ++j) { float v = acc[j] + bb; ps += v; pq += v * v; }
    atomicAdd(&sS[g], ps);
    atomicAdd(&sQ[g], pq);
    __syncthreads();
    if (t < NGR) {
      atomicAdd(&dst[b * NGR + t], (double)sS[t]);
      atomicAdd(&dst[32 + b * NGR + t], (double)sQ[t]);
    }
  } else {
    float mu = fmu[b * NGR + g], rs = frs[b * NGR + g];
    float ga = g0[o], be = be0[o];
    float m = -3.4e38f;
#pragma unroll
    for (int j = 0; j < 16; ++j) {
      float v = acc[j] + bb;
      v = (v - mu) * rs * ga + be;
      v = v / (1.f + expf(-v));
      m = fmaxf(m, v);
    }
    if (kh == 0) maxL[o] = m;
    __syncthreads();
    if (kh == 1) xp[(size_t)bs * 128 + o] = fmaxf(maxL[o], m);
  }
}

// ---------------- finalize group stats: mu, rsqrt(var+eps) ----------------
__global__ void k_fin(const double* __restrict__ dst, float* __restrict__ fmu,
                      float* __restrict__ frs, double cntInv) {
  int i = threadIdx.x;
  if (i >= BB * NGR) return;
  double m = dst[i] * cntInv;
  double q = dst[32 + i] * cntInv;
  double var = q - m * m;
  fmu[i] = (float)m;
  frs[i] = (float)rsqrt(var + 1e-5);
}

// ---------------- MLP1: h1 = w1 @ xp + b1, accumulate gn1 stats ----------------
__global__ __launch_bounds__(256) void k_mlp1(
    const float* __restrict__ xp, const float* __restrict__ w1t,
    const float* __restrict__ b1, float* __restrict__ h1, double* __restrict__ dst) {
  __shared__ __align__(16) float xpL[8 * 128];
  __shared__ float sS[NGR], sQ[NGR];
  int t = threadIdx.x;
  int bs0 = blockIdx.x * 8;
  int b = bs0 >> 11;
  if (t < NGR) { sS[t] = 0.f; sQ[t] = 0.f; }
  {
    int idx4 = t >> 5, l = t & 31;
    ((float4*)xpL)[idx4 * 32 + l] = ((const float4*)(xp + (size_t)bs0 * 128))[idx4 * 32 + l];
  }
  __syncthreads();
  float acc0[8], acc1[8];
#pragma unroll
  for (int i = 0; i < 8; ++i) { acc0[i] = 0.f; acc1[i] = 0.f; }
  for (int c4 = 0; c4 < 32; ++c4) {
    float wa0 = w1t[(c4 * 4 + 0) * 512 + t];
    float wa1 = w1t[(c4 * 4 + 1) * 512 + t];
    float wa2 = w1t[(c4 * 4 + 2) * 512 + t];
    float wa3 = w1t[(c4 * 4 + 3) * 512 + t];
    float wb0 = w1t[(c4 * 4 + 0) * 512 + 256 + t];
    float wb1 = w1t[(c4 * 4 + 1) * 512 + 256 + t];
    float wb2 = w1t[(c4 * 4 + 2) * 512 + 256 + t];
    float wb3 = w1t[(c4 * 4 + 3) * 512 + 256 + t];
#pragma unroll
    for (int si = 0; si < 8; ++si) {
      float4 xv = *(const float4*)(xpL + si * 128 + c4 * 4);
      acc0[si] = fmaf(wa0, xv.x, acc0[si]);
      acc0[si] = fmaf(wa1, xv.y, acc0[si]);
      acc0[si] = fmaf(wa2, xv.z, acc0[si]);
      acc0[si] = fmaf(wa3, xv.w, acc0[si]);
      acc1[si] = fmaf(wb0, xv.x, acc1[si]);
      acc1[si] = fmaf(wb1, xv.y, acc1[si]);
      acc1[si] = fmaf(wb2, xv.z, acc1[si]);
      acc1[si] = fmaf(wb3, xv.w, acc1[si]);
    }
  }
  float ba = b1[t], bbv = b1[256 + t];
  float ps0 = 0.f, pq0 = 0.f, ps1 = 0.f, pq1 = 0.f;
#pragma unroll
  for (int si = 0; si < 8; ++si) {
    float va = acc0[si] + ba;
    float vb = acc1[si] + bbv;
    h1[(size_t)(bs0 + si) * 512 + t] = va;
    h1[(size_t)(bs0 + si) * 512 + 256 + t] = vb;
    ps0 += va; pq0 += va * va;
    ps1 += vb; pq1 += vb * vb;
  }
  atomicAdd(&sS[t >> 6], ps0);
  atomicAdd(&sQ[t >> 6], pq0);
  atomicAdd(&sS[4 + (t >> 6)], ps1);
  atomicAdd(&sQ[4 + (t >> 6)], pq1);
  __syncthreads();
  if (t < NGR) {
    atomicAdd(&dst[b * NGR + t], (double)sS[t]);
    atomicAdd(&dst[32 + b * NGR + t], (double)sQ[t]);
  }
}

// ---------------- MLP2: h2 = w2 @ silu(gn1(h1)) + b2, accumulate gn2 stats ----------------
__global__ __launch_bounds__(256) void k_mlp2(
    const float* __restrict__ h1, const float* __restrict__ w2t,
    const float* __restrict__ b2, const float* __restrict__ fmu1, const float* __restrict__ frs1,
    const float* __restrict__ g1, const float* __restrict__ be1,
    float* __restrict__ h2, double* __restrict__ dst) {
  __shared__ __align__(16) float hL[8 * 512];
  __shared__ float sS[NGR], sQ[NGR];
  int t = threadIdx.x;
  int bs0 = blockIdx.x * 8;
  int b = bs0 >> 11;
  if (t < NGR) { sS[t] = 0.f; sQ[t] = 0.f; }
  {
    int si = t >> 5, l = t & 31;
    int c0 = l * 16;
    int g = c0 >> 6;
    float mu = fmu1[b * NGR + g], rs = frs1[b * NGR + g];
    const float* src = h1 + (size_t)(bs0 + si) * 512 + c0;
#pragma unroll
    for (int j = 0; j < 16; ++j) {
      float v = src[j];
      v = (v - mu) * rs * g1[c0 + j] + be1[c0 + j];
      v = v / (1.f + expf(-v));
      hL[si * 512 + c0 + j] = v;
    }
  }
  __syncthreads();
  int o = t & 127, sh = t >> 7;
  float acc[4] = {0.f, 0.f, 0.f, 0.f};
  for (int c4 = 0; c4 < 128; ++c4) {
    float w0v = w2t[(c4 * 4 + 0) * 128 + o];
    float w1v = w2t[(c4 * 4 + 1) * 128 + o];
    float w2v = w2t[(c4 * 4 + 2) * 128 + o];
    float w3v = w2t[(c4 * 4 + 3) * 128 + o];
#pragma unroll
    for (int m = 0; m < 4; ++m) {
      float4 hq = *(const float4*)(hL + (sh * 4 + m) * 512 + c4 * 4);
      acc[m] = fmaf(w0v, hq.x, acc[m]);
      acc[m] = fmaf(w1v, hq.y, acc[m]);
      acc[m] = fmaf(w2v, hq.z, acc[m]);
      acc[m] = fmaf(w3v, hq.w, acc[m]);
    }
  }
  float bb = b2[o];
  float ps = 0.f, pq = 0.f;
#pragma unroll
  for (int m = 0; m < 4; ++m) {
    float v = acc[m] + bb;
    h2[(size_t)(bs0 + sh * 4 + m) * 128 + o] = v;
    ps += v; pq += v * v;
  }
  atomicAdd(&sS[o >> 4], ps);
  atomicAdd(&sQ[o >> 4], pq);
  __syncthreads();
  if (t < NGR) {
    atomicAdd(&dst[b * NGR + t], (double)sS[t]);
    atomicAdd(&dst[32 + b * NGR + t], (double)sQ[t]);
  }
}

// ---------------- final: gn2 + modulation + residual ----------------
__global__ void k_final(const float* __restrict__ h2, const float* __restrict__ xp,
                        const float* __restrict__ fmu2, const float* __restrict__ frs2,
                        const float* __restrict__ g2, const float* __restrict__ be2,
                        const float* __restrict__ scl, const float* __restrict__ shf,
                        float* __restrict__ out) {
  int f = blockIdx.x * 256 + threadIdx.x;
  if (f >= BB * 128 * SS) return;
  int s = f & (SS - 1);
  int o = (f >> 11) & 127;
  int b = f >> 18;
  int g = o >> 4;
  float v = h2[((size_t)b * SS + s) * 128 + o];
  v = (v - fmu2[b * NGR + g]) * frs2[b * NGR + g] * g2[o] + be2[o];
  float idv = xp[((size_t)b * SS + s) * 128 + o];
  out[f] = v * (1.f + scl[b * 128 + o]) + shf[b * 128 + o] + idv;
}

extern "C" void kernel_launch(void* const* d_in, const int* in_sizes, int n_in,
                              void* d_out, int out_size, void* d_ws, size_t ws_size,
                              hipStream_t stream) {
  const float* xyz = (const float*)d_in[0];
  const float* pts = (const float*)d_in[1];
  const float* te = (const float*)d_in[2];
  const float* ce = (const float*)d_in[3];
  const float* w0 = (const float*)d_in[4];
  const float* b0 = (const float*)d_in[5];
  const float* g0 = (const float*)d_in[6];
  const float* be0 = (const float*)d_in[7];
  const float* w1 = (const float*)d_in[8];
  const float* b1 = (const float*)d_in[9];
  const float* g1 = (const float*)d_in[10];
  const float* be1 = (const float*)d_in[11];
  const float* w2 = (const float*)d_in[12];
  const float* b2 = (const float*)d_in[13];
  const float* g2 = (const float*)d_in[14];
  const float* be2 = (const float*)d_in[15];
  const float* wt = (const float*)d_in[16];
  const float* bt = (const float*)d_in[17];
  const float* wc = (const float*)d_in[18];
  const float* bc = (const float*)d_in[19];

  char* ws = (char*)d_ws;
  size_t off = 0;
  auto alloc = [&](size_t bytes) {
    void* p = ws + off;
    off += (bytes + 255) & ~(size_t)255;
    return p;
  };
  float* ptst = (float*)alloc((size_t)BB * NN * 64 * 4);
  float* sqn = (float*)alloc((size_t)BB * NN * 4);
  int* gi = (int*)alloc((size_t)BB * SS * KK * 4);
  float* xp = (float*)alloc((size_t)BB * SS * 128 * 4);
  float* h1 = (float*)alloc((size_t)BB * SS * 512 * 4);
  float* h2 = (float*)alloc((size_t)BB * SS * 128 * 4);
  float* w1t = (float*)alloc(512 * 128 * 4);
  float* w2t = (float*)alloc(512 * 128 * 4);
  float* scl = (float*)alloc(BB * 128 * 4);
  float* shf = (float*)alloc(BB * 128 * 4);
  double* dstat = (double*)alloc(3 * 64 * 8);
  float* fmu = (float*)alloc(3 * 32 * 4);
  float* frs = (float*)alloc(3 * 32 * 4);

  float* newxyz = (float*)d_out;
  float* outnp = (float*)d_out + (size_t)BB * 3 * SS;

  hipMemsetAsync(dstat, 0, 3 * 64 * 8, stream);
  k_sqn<<<BB * NN / 256, 256, 0, stream>>>(xyz, sqn);
  k_tr<<<dim3(NN / 64, BB), 256, 0, stream>>>(pts, ptst);
  k_wt<<<(512 * 128 + 255) / 256, 256, 0, stream>>>(w1, w1t, 512, 128);
  k_wt<<<(512 * 128 + 255) / 256, 256, 0, stream>>>(w2, w2t, 128, 512);
  k_mod<<<2, 256, 0, stream>>>(te, ce, wt, bt, wc, bc, scl, shf);
  k_fps<<<BB, FT, 0, stream>>>(xyz, newxyz);
  k_ballq<<<BB * SS / 4, 256, 0, stream>>>(xyz, sqn, newxyz, gi);
  k_mlp0<0><<<BB * SS, 256, 0, stream>>>(xyz, ptst, newxyz, gi, w0, b0, dstat, fmu, frs, g0, be0, xp);
  k_fin<<<1, 64, 0, stream>>>(dstat, fmu, frs, 1.0 / (16.0 * SS * KK));
  k_mlp0<1><<<BB * SS, 256, 0, stream>>>(xyz, ptst, newxyz, gi, w0, b0, dstat, fmu, frs, g0, be0, xp);
  k_mlp1<<<BB * SS / 8, 256, 0, stream>>>(xp, w1t, b1, h1, dstat + 64);
  k_fin<<<1, 64, 0, stream>>>(dstat + 64, fmu + 32, frs + 32, 1.0 / (64.0 * SS));
  k_mlp2<<<BB * SS / 8, 256, 0, stream>>>(h1, w2t, b2, fmu + 32, frs + 32, g1, be1, h2, dstat + 128);
  k_fin<<<1, 64, 0, stream>>>(dstat + 128, fmu + 64, frs + 64, 1.0 / (16.0 * SS));
  k_final<<<BB * 128 * SS / 256, 256, 0, stream>>>(h2, xp, fmu + 64, frs + 64, g2, be2, scl, shf, outnp);
}

// Round 14
// 2220.646 us; speedup vs baseline: 1.1670x; 1.0486x over previous
//
#include <hip/hip_runtime.h>
#include <math.h>

#define BB 4
#define NN 8192
#define SS 2048
#define KK 32
#define NGR 8

// ---------------- fused FPS + prep (sqn / tr / wt / mod as extra blocks) ----------------
// r13 post-mortem: 2 waves/SIMD duplicate all per-wave reduce overhead; u64
// DPP tree costs 5 instr/step. r14: FT=256 (1 wave/SIMD, pinning keeps pts
// resident), split u32-max/i32-min reduction (dist>=0 so f32 bits order as
// u32; min-index-among-bit-equal-maxima == first-occurrence argmax), and prep
// kernels fused in as extra blocks on idle CUs (FPS uses only 4 of 256).
template <int CTRL>
__device__ __forceinline__ unsigned umaxdpp(unsigned v) {
  int o = __builtin_amdgcn_update_dpp((int)v, (int)v, CTRL, 0xf, 0xf, false);
  unsigned u = (unsigned)o;
  return u > v ? u : v;
}
template <int CTRL>
__device__ __forceinline__ int imindpp(int v) {
  int o = __builtin_amdgcn_update_dpp(v, v, CTRL, 0xf, 0xf, false);
  return o < v ? o : v;
}

#define FT 256
#define FPT (NN / FT)   // 32 points per thread
#define FW (FT / 64)    // 4 waves

#define NB_SQN (BB * NN / 256)        // 128
#define NB_TR ((NN / 64) * BB)        // 512
#define NB_WT 32
#define NB_MOD 2
#define NB_TOTAL (BB + NB_SQN + NB_TR + NB_WT + NB_MOD)

__global__ __launch_bounds__(FT, 1) void k_fps(
    const float* __restrict__ xyz, float* __restrict__ newxyz,
    float* __restrict__ sqn, const float* __restrict__ pts, float* __restrict__ ptst,
    const float* __restrict__ w1, float* __restrict__ w1t,
    const float* __restrict__ w2, float* __restrict__ w2t,
    const float* __restrict__ te, const float* __restrict__ ce,
    const float* __restrict__ wt, const float* __restrict__ bt,
    const float* __restrict__ wc, const float* __restrict__ bc,
    float* __restrict__ scl, float* __restrict__ shf) {
  __shared__ float4 p4[NN];            // 128 KB point store (FPS) / tr tile scratch
  __shared__ int fars[SS];             // 8 KB chosen indices
  __shared__ unsigned wkd[2][FW];      // wave max-dist bits (parity dbuf)
  __shared__ int wki[2][FW];           // wave min-idx among ties
  int t = threadIdx.x;
  int bid = blockIdx.x;

  if (bid < BB) {
    // ---------------- FPS role ----------------
    int b = bid;
    const float* gx = xyz + (size_t)b * 3 * NN;
    const float* gy = gx + NN;
    const float* gz = gx + 2 * NN;
    for (int i = t; i < NN; i += FT)
      p4[i] = make_float4(gx[i], gy[i], gz[i], 0.f);
    float px[FPT], py[FPT], pz[FPT], dm[FPT];
#pragma unroll
    for (int j = 0; j < FPT; ++j) {
      px[j] = gx[t + j * FT];
      py[j] = gy[t + j * FT];
      pz[j] = gz[t + j * FT];
      dm[j] = 1e10f;
      // pin in VGPRs so the loads can't be rematerialized into the loop (r11)
      asm volatile("" : "+v"(px[j]), "+v"(py[j]), "+v"(pz[j]));
    }
    __syncthreads();
    int far = 0;
    for (int k = 0; k < SS; ++k) {
      float4 c = p4[far];          // uniform addr -> LDS broadcast
      if (t == 0) fars[k] = far;   // LDS only: no vmcnt drain at the barrier
      float bv = -1.f;
      int jb = 0;
#pragma unroll
      for (int j = 0; j < FPT; ++j) {
        float dx = __fsub_rn(px[j], c.x);
        float dy = __fsub_rn(py[j], c.y);
        float dz = __fsub_rn(pz[j], c.z);
        float d = __fadd_rn(__fadd_rn(__fmul_rn(dx, dx), __fmul_rn(dy, dy)), __fmul_rn(dz, dz));
        float m = fminf(dm[j], d);
        dm[j] = m;
        if (m > bv) { bv = m; jb = j; }  // strict >; keeps smallest j on ties
      }
      int bp = t + jb * FT;
      // dist >= 0 -> f32 bits order as u32. Wave max tree (lane63 = wave max).
      unsigned bvb = __float_as_uint(bv);
      unsigned kv = bvb;
      kv = umaxdpp<0xB1>(kv);   // xor 1
      kv = umaxdpp<0x4E>(kv);   // xor 2
      kv = umaxdpp<0x141>(kv);  // row_half_mirror
      kv = umaxdpp<0x140>(kv);  // row_mirror -> row max
      kv = umaxdpp<0x142>(kv);  // row_bcast15
      kv = umaxdpp<0x143>(kv);  // row_bcast31 -> lane63 = wave max
      unsigned wmb = (unsigned)__builtin_amdgcn_readlane((int)kv, 63);
      // min index among lanes whose bv equals the wave max (first-occurrence)
      int cand = (bvb == wmb) ? bp : 0x7fffffff;
      cand = imindpp<0xB1>(cand);
      cand = imindpp<0x4E>(cand);
      cand = imindpp<0x141>(cand);
      cand = imindpp<0x140>(cand);
      cand = imindpp<0x142>(cand);
      cand = imindpp<0x143>(cand);  // lane63 = wave min-idx
      if ((t & 63) == 63) { wkd[k & 1][t >> 6] = wmb; wki[k & 1][t >> 6] = cand; }
      __syncthreads();
      // lane-parallel merge over FW=4 wave keys: 2-step butterfly
      unsigned md = wkd[k & 1][t & (FW - 1)];
      int mi = wki[k & 1][t & (FW - 1)];
      unsigned bm = md;
      bm = umaxdpp<0xB1>(bm);
      bm = umaxdpp<0x4E>(bm);   // all lanes in 4-group have block max
      int c2 = (md == bm) ? mi : 0x7fffffff;
      c2 = imindpp<0xB1>(c2);
      c2 = imindpp<0x4E>(c2);   // block min idx among ties
      far = __builtin_amdgcn_readfirstlane(c2);
    }
    __syncthreads();
    float* ox = newxyz + (size_t)b * 3 * SS;
    for (int k = t; k < SS; k += FT) {
      float4 c = p4[fars[k]];
      ox[k] = c.x; ox[SS + k] = c.y; ox[2 * SS + k] = c.z;
    }
    return;
  }
  bid -= BB;

  if (bid < NB_SQN) {
    // ---------------- sqn role: per-point squared norm (strict rounding) ----------------
    int i = bid * 256 + t;
    int b = i >> 13, n = i & (NN - 1);
    const float* p = xyz + (size_t)b * 3 * NN;
    float x = p[n], y = p[NN + n], z = p[2 * NN + n];
    sqn[i] = __fadd_rn(__fadd_rn(__fmul_rn(x, x), __fmul_rn(y, y)), __fmul_rn(z, z));
    return;
  }
  bid -= NB_SQN;

  if (bid < NB_TR) {
    // ---------------- tr role: points (B,64,N) -> (B,N,64) ----------------
    float* tile = (float*)p4;  // [64][65] scratch
    int b = bid >> 7;
    int n0 = (bid & 127) << 6;
    {
      int n = t & 63, cq = t >> 6;
      for (int j = 0; j < 16; ++j) {
        int c = cq * 16 + j;
        tile[c * 65 + n] = pts[((size_t)b * 64 + c) * NN + n0 + n];
      }
    }
    __syncthreads();
    {
      int c = t & 63, nq = t >> 6;
      for (int j = 0; j < 16; ++j) {
        int nn2 = nq * 16 + j;
        ptst[((size_t)b * NN + n0 + nn2) * 64 + c] = tile[c * 65 + nn2];
      }
    }
    return;
  }
  bid -= NB_TR;

  if (bid < NB_WT) {
    // ---------------- wt role: weight transposes (grid-stride over both) ----------------
    for (int i = bid * 256 + t; i < 512 * 128; i += NB_WT * 256) {
      int r = i >> 7, c = i & 127;           // w1: rows=512, cols=128
      w1t[c * 512 + r] = w1[i];
      int r2 = i >> 9, c2 = i & 511;         // w2: rows=128, cols=512
      w2t[c2 * 128 + r2] = w2[i];
    }
    return;
  }
  bid -= NB_WT;

  {
    // ---------------- mod role: scale/shift from t_emb/c_emb ----------------
    int tg = bid * 256 + t;
    int b = tg >> 7, o = tg & 127;
    const float* tb = te + b * 128;
    const float* cb = ce + b * 128;
    float s1 = 0.f, s2 = 0.f, h1 = 0.f, h2 = 0.f;
    for (int c = 0; c < 128; ++c) {
      float tv = tb[c], cv = cb[c];
      s1 = fmaf(tv, wt[o * 128 + c], s1);
      h1 = fmaf(tv, wt[(o + 128) * 128 + c], h1);
      s2 = fmaf(cv, wc[o * 128 + c], s2);
      h2 = fmaf(cv, wc[(o + 128) * 128 + c], h2);
    }
    scl[tg] = s1 + bt[o] + s2 + bc[o];
    shf[tg] = h1 + bt[o + 128] + h2 + bc[o + 128];
  }
}

// ---------------- ball query: 1 wave per center, ordered scan + ballot compact ----------------
__global__ __launch_bounds__(256) void k_ballq(const float* __restrict__ xyz,
                                               const float* __restrict__ sqn,
                                               const float* __restrict__ newxyz,
                                               int* __restrict__ gi) {
  int wid = (blockIdx.x * 256 + threadIdx.x) >> 6;
  int lane = threadIdx.x & 63;
  if (wid >= BB * SS) return;
  int b = wid >> 11, s = wid & (SS - 1);
  const float* nx = newxyz + (size_t)b * 3 * SS;
  float sx = nx[s], sy = nx[SS + s], sz = nx[2 * SS + s];
  float ss = __fadd_rn(__fadd_rn(__fmul_rn(sx, sx), __fmul_rn(sy, sy)), __fmul_rn(sz, sz));
  const float* gx = xyz + (size_t)b * 3 * NN;
  const float* gy = gx + NN;
  const float* gz = gx + 2 * NN;
  const float* sn = sqn + (size_t)b * NN;
  int* go = gi + (size_t)wid * KK;
  int found = 0, first = 0;
  for (int n0 = 0; n0 < NN && found < KK; n0 += 64) {
    int n = n0 + lane;
    float x = gx[n], y = gy[n], z = gz[n];
    float ip = __fmul_rn(sx, x);
    ip = __fmaf_rn(sy, y, ip);
    ip = __fmaf_rn(sz, z, ip);
    float d = __fsub_rn(__fadd_rn(ss, sn[n]), __fmul_rn(2.0f, ip));
    bool pred = (d <= 0.25f);
    unsigned long long m = __ballot(pred);
    if (found == 0 && m) first = n0 + __ffsll((unsigned long long)m) - 1;
    if (pred) {
      int pos = found + __popcll(m & ((1ull << lane) - 1ull));
      if (pos < KK) go[pos] = n;
    }
    found += __popcll(m);
  }
  for (int p = found + lane; p < KK; p += 64) go[p] = first;
}

// ---------------- MLP0 (gather + W0*feat), PASS 0: stats, PASS 1: norm+silu+maxpool ----------------
template <int PASS>
__global__ __launch_bounds__(256) void k_mlp0(
    const float* __restrict__ xyz, const float* __restrict__ ptst,
    const float* __restrict__ newxyz, const int* __restrict__ gi,
    const float* __restrict__ w0, const float* __restrict__ b0,
    double* __restrict__ dst, const float* __restrict__ fmu, const float* __restrict__ frs,
    const float* __restrict__ g0, const float* __restrict__ be0,
    float* __restrict__ xp) {
  __shared__ __align__(16) float w0L[128 * 67];
  __shared__ __align__(16) float featL[67 * 36];
  __shared__ int giL[KK];
  __shared__ float sS[NGR], sQ[NGR];
  __shared__ float maxL[128];
  int t = threadIdx.x;
  int bs = blockIdx.x;
  int b = bs >> 11;
  int s = bs & (SS - 1);
  for (int i = t; i < 128 * 67; i += 256) w0L[i] = w0[i];
  if (t < KK) giL[t] = gi[(size_t)bs * KK + t];
  if (PASS == 0 && t < NGR) { sS[t] = 0.f; sQ[t] = 0.f; }
  __syncthreads();
  {
    int k = t & 31, q = t >> 5;
    int idx = giL[k];
    const float4* src = (const float4*)(ptst + ((size_t)b * NN + idx) * 64 + q * 8);
    float4 v0 = src[0], v1 = src[1];
    int cb = 3 + q * 8;
    featL[(cb + 0) * 36 + k] = v0.x;
    featL[(cb + 1) * 36 + k] = v0.y;
    featL[(cb + 2) * 36 + k] = v0.z;
    featL[(cb + 3) * 36 + k] = v0.w;
    featL[(cb + 4) * 36 + k] = v1.x;
    featL[(cb + 5) * 36 + k] = v1.y;
    featL[(cb + 6) * 36 + k] = v1.z;
    featL[(cb + 7) * 36 + k] = v1.w;
    if (q == 0) {
      const float* gx = xyz + (size_t)b * 3 * NN;
      const float* nx = newxyz + (size_t)b * 3 * SS;
      featL[0 * 36 + k] = gx[idx] - nx[s];
      featL[1 * 36 + k] = gx[NN + idx] - nx[SS + s];
      featL[2 * 36 + k] = gx[2 * NN + idx] - nx[2 * SS + s];
    }
  }
  __syncthreads();
  int o = t & 127, kh = t >> 7;
  float acc[16];
#pragma unroll
  for (int j = 0; j < 16; ++j) acc[j] = 0.f;
  const float* wrow = w0L + o * 67;
  const float* fb = featL + kh * 16;
  for (int c = 0; c < 67; ++c) {
    float w = wrow[c];
    const float4* f4 = (const float4*)(fb + c * 36);
    float4 a = f4[0], b4 = f4[1], c4 = f4[2], d4 = f4[3];
    acc[0] = fmaf(w, a.x, acc[0]);    acc[1] = fmaf(w, a.y, acc[1]);
    acc[2] = fmaf(w, a.z, acc[2]);    acc[3] = fmaf(w, a.w, acc[3]);
    acc[4] = fmaf(w, b4.x, acc[4]);   acc[5] = fmaf(w, b4.y, acc[5]);
    acc[6] = fmaf(w, b4.z, acc[6]);   acc[7] = fmaf(w, b4.w, acc[7]);
    acc[8] = fmaf(w, c4.x, acc[8]);   acc[9] = fmaf(w, c4.y, acc[9]);
    acc[10] = fmaf(w, c4.z, acc[10]); acc[11] = fmaf(w, c4.w, acc[11]);
    acc[12] = fmaf(w, d4.x, acc[12]); acc[13] = fmaf(w, d4.y, acc[13]);
    acc[14] = fmaf(w, d4.z, acc[14]); acc[15] = fmaf(w, d4.w, acc[15]);
  }
  float bb = b0[o];
  int g = o >> 4;
  if (PASS == 0) {
    float ps = 0.f, pq = 0.f;
#pragma unroll
    for (int j = 0; j < 16; ++j) { float v = acc[j] + bb; ps += v; pq += v * v; }
    atomicAdd(&sS[g], ps);
    atomicAdd(&sQ[g], pq);
    __syncthreads();
    if (t < NGR) {
      atomicAdd(&dst[b * NGR + t], (double)sS[t]);
      atomicAdd(&dst[32 + b * NGR + t], (double)sQ[t]);
    }
  } else {
    float mu = fmu[b * NGR + g], rs = frs[b * NGR + g];
    float ga = g0[o], be = be0[o];
    float m = -3.4e38f;
#pragma unroll
    for (int j = 0; j < 16; ++j) {
      float v = acc[j] + bb;
      v = (v - mu) * rs * ga + be;
      v = v / (1.f + expf(-v));
      m = fmaxf(m, v);
    }
    if (kh == 0) maxL[o] = m;
    __syncthreads();
    if (kh == 1) xp[(size_t)bs * 128 + o] = fmaxf(maxL[o], m);
  }
}

// ---------------- finalize group stats: mu, rsqrt(var+eps) ----------------
__global__ void k_fin(const double* __restrict__ dst, float* __restrict__ fmu,
                      float* __restrict__ frs, double cntInv) {
  int i = threadIdx.x;
  if (i >= BB * NGR) return;
  double m = dst[i] * cntInv;
  double q = dst[32 + i] * cntInv;
  double var = q - m * m;
  fmu[i] = (float)m;
  frs[i] = (float)rsqrt(var + 1e-5);
}

// ---------------- MLP1: h1 = w1 @ xp + b1, accumulate gn1 stats ----------------
__global__ __launch_bounds__(256) void k_mlp1(
    const float* __restrict__ xp, const float* __restrict__ w1t,
    const float* __restrict__ b1, float* __restrict__ h1, double* __restrict__ dst) {
  __shared__ __align__(16) float xpL[8 * 128];
  __shared__ float sS[NGR], sQ[NGR];
  int t = threadIdx.x;
  int bs0 = blockIdx.x * 8;
  int b = bs0 >> 11;
  if (t < NGR) { sS[t] = 0.f; sQ[t] = 0.f; }
  {
    int idx4 = t >> 5, l = t & 31;
    ((float4*)xpL)[idx4 * 32 + l] = ((const float4*)(xp + (size_t)bs0 * 128))[idx4 * 32 + l];
  }
  __syncthreads();
  float acc0[8], acc1[8];
#pragma unroll
  for (int i = 0; i < 8; ++i) { acc0[i] = 0.f; acc1[i] = 0.f; }
  for (int c4 = 0; c4 < 32; ++c4) {
    float wa0 = w1t[(c4 * 4 + 0) * 512 + t];
    float wa1 = w1t[(c4 * 4 + 1) * 512 + t];
    float wa2 = w1t[(c4 * 4 + 2) * 512 + t];
    float wa3 = w1t[(c4 * 4 + 3) * 512 + t];
    float wb0 = w1t[(c4 * 4 + 0) * 512 + 256 + t];
    float wb1 = w1t[(c4 * 4 + 1) * 512 + 256 + t];
    float wb2 = w1t[(c4 * 4 + 2) * 512 + 256 + t];
    float wb3 = w1t[(c4 * 4 + 3) * 512 + 256 + t];
#pragma unroll
    for (int si = 0; si < 8; ++si) {
      float4 xv = *(const float4*)(xpL + si * 128 + c4 * 4);
      acc0[si] = fmaf(wa0, xv.x, acc0[si]);
      acc0[si] = fmaf(wa1, xv.y, acc0[si]);
      acc0[si] = fmaf(wa2, xv.z, acc0[si]);
      acc0[si] = fmaf(wa3, xv.w, acc0[si]);
      acc1[si] = fmaf(wb0, xv.x, acc1[si]);
      acc1[si] = fmaf(wb1, xv.y, acc1[si]);
      acc1[si] = fmaf(wb2, xv.z, acc1[si]);
      acc1[si] = fmaf(wb3, xv.w, acc1[si]);
    }
  }
  float ba = b1[t], bbv = b1[256 + t];
  float ps0 = 0.f, pq0 = 0.f, ps1 = 0.f, pq1 = 0.f;
#pragma unroll
  for (int si = 0; si < 8; ++si) {
    float va = acc0[si] + ba;
    float vb = acc1[si] + bbv;
    h1[(size_t)(bs0 + si) * 512 + t] = va;
    h1[(size_t)(bs0 + si) * 512 + 256 + t] = vb;
    ps0 += va; pq0 += va * va;
    ps1 += vb; pq1 += vb * vb;
  }
  atomicAdd(&sS[t >> 6], ps0);
  atomicAdd(&sQ[t >> 6], pq0);
  atomicAdd(&sS[4 + (t >> 6)], ps1);
  atomicAdd(&sQ[4 + (t >> 6)], pq1);
  __syncthreads();
  if (t < NGR) {
    atomicAdd(&dst[b * NGR + t], (double)sS[t]);
    atomicAdd(&dst[32 + b * NGR + t], (double)sQ[t]);
  }
}

// ---------------- MLP2: h2 = w2 @ silu(gn1(h1)) + b2, accumulate gn2 stats ----------------
__global__ __launch_bounds__(256) void k_mlp2(
    const float* __restrict__ h1, const float* __restrict__ w2t,
    const float* __restrict__ b2, const float* __restrict__ fmu1, const float* __restrict__ frs1,
    const float* __restrict__ g1, const float* __restrict__ be1,
    float* __restrict__ h2, double* __restrict__ dst) {
  __shared__ __align__(16) float hL[8 * 512];
  __shared__ float sS[NGR], sQ[NGR];
  int t = threadIdx.x;
  int bs0 = blockIdx.x * 8;
  int b = bs0 >> 11;
  if (t < NGR) { sS[t] = 0.f; sQ[t] = 0.f; }
  {
    int si = t >> 5, l = t & 31;
    int c0 = l * 16;
    int g = c0 >> 6;
    float mu = fmu1[b * NGR + g], rs = frs1[b * NGR + g];
    const float* src = h1 + (size_t)(bs0 + si) * 512 + c0;
#pragma unroll
    for (int j = 0; j < 16; ++j) {
      float v = src[j];
      v = (v - mu) * rs * g1[c0 + j] + be1[c0 + j];
      v = v / (1.f + expf(-v));
      hL[si * 512 + c0 + j] = v;
    }
  }
  __syncthreads();
  int o = t & 127, sh = t >> 7;
  float acc[4] = {0.f, 0.f, 0.f, 0.f};
  for (int c4 = 0; c4 < 128; ++c4) {
    float w0v = w2t[(c4 * 4 + 0) * 128 + o];
    float w1v = w2t[(c4 * 4 + 1) * 128 + o];
    float w2v = w2t[(c4 * 4 + 2) * 128 + o];
    float w3v = w2t[(c4 * 4 + 3) * 128 + o];
#pragma unroll
    for (int m = 0; m < 4; ++m) {
      float4 hq = *(const float4*)(hL + (sh * 4 + m) * 512 + c4 * 4);
      acc[m] = fmaf(w0v, hq.x, acc[m]);
      acc[m] = fmaf(w1v, hq.y, acc[m]);
      acc[m] = fmaf(w2v, hq.z, acc[m]);
      acc[m] = fmaf(w3v, hq.w, acc[m]);
    }
  }
  float bb = b2[o];
  float ps = 0.f, pq = 0.f;
#pragma unroll
  for (int m = 0; m < 4; ++m) {
    float v = acc[m] + bb;
    h2[(size_t)(bs0 + sh * 4 + m) * 128 + o] = v;
    ps += v; pq += v * v;
  }
  atomicAdd(&sS[o >> 4], ps);
  atomicAdd(&sQ[o >> 4], pq);
  __syncthreads();
  if (t < NGR) {
    atomicAdd(&dst[b * NGR + t], (double)sS[t]);
    atomicAdd(&dst[32 + b * NGR + t], (double)sQ[t]);
  }
}

// ---------------- final: gn2 + modulation + residual ----------------
__global__ void k_final(const float* __restrict__ h2, const float* __restrict__ xp,
                        const float* __restrict__ fmu2, const float* __restrict__ frs2,
                        const float* __restrict__ g2, const float* __restrict__ be2,
                        const float* __restrict__ scl, const float* __restrict__ shf,
                        float* __restrict__ out) {
  int f = blockIdx.x * 256 + threadIdx.x;
  if (f >= BB * 128 * SS) return;
  int s = f & (SS - 1);
  int o = (f >> 11) & 127;
  int b = f >> 18;
  int g = o >> 4;
  float v = h2[((size_t)b * SS + s) * 128 + o];
  v = (v - fmu2[b * NGR + g]) * frs2[b * NGR + g] * g2[o] + be2[o];
  float idv = xp[((size_t)b * SS + s) * 128 + o];
  out[f] = v * (1.f + scl[b * 128 + o]) + shf[b * 128 + o] + idv;
}

extern "C" void kernel_launch(void* const* d_in, const int* in_sizes, int n_in,
                              void* d_out, int out_size, void* d_ws, size_t ws_size,
                              hipStream_t stream) {
  const float* xyz = (const float*)d_in[0];
  const float* pts = (const float*)d_in[1];
  const float* te = (const float*)d_in[2];
  const float* ce = (const float*)d_in[3];
  const float* w0 = (const float*)d_in[4];
  const float* b0 = (const float*)d_in[5];
  const float* g0 = (const float*)d_in[6];
  const float* be0 = (const float*)d_in[7];
  const float* w1 = (const float*)d_in[8];
  const float* b1 = (const float*)d_in[9];
  const float* g1 = (const float*)d_in[10];
  const float* be1 = (const float*)d_in[11];
  const float* w2 = (const float*)d_in[12];
  const float* b2 = (const float*)d_in[13];
  const float* g2 = (const float*)d_in[14];
  const float* be2 = (const float*)d_in[15];
  const float* wt = (const float*)d_in[16];
  const float* bt = (const float*)d_in[17];
  const float* wc = (const float*)d_in[18];
  const float* bc = (const float*)d_in[19];

  char* ws = (char*)d_ws;
  size_t off = 0;
  auto alloc = [&](size_t bytes) {
    void* p = ws + off;
    off += (bytes + 255) & ~(size_t)255;
    return p;
  };
  float* ptst = (float*)alloc((size_t)BB * NN * 64 * 4);
  float* sqn = (float*)alloc((size_t)BB * NN * 4);
  int* gi = (int*)alloc((size_t)BB * SS * KK * 4);
  float* xp = (float*)alloc((size_t)BB * SS * 128 * 4);
  float* h1 = (float*)alloc((size_t)BB * SS * 512 * 4);
  float* h2 = (float*)alloc((size_t)BB * SS * 128 * 4);
  float* w1t = (float*)alloc(512 * 128 * 4);
  float* w2t = (float*)alloc(512 * 128 * 4);
  float* scl = (float*)alloc(BB * 128 * 4);
  float* shf = (float*)alloc(BB * 128 * 4);
  double* dstat = (double*)alloc(3 * 64 * 8);
  float* fmu = (float*)alloc(3 * 32 * 4);
  float* frs = (float*)alloc(3 * 32 * 4);

  float* newxyz = (float*)d_out;
  float* outnp = (float*)d_out + (size_t)BB * 3 * SS;

  hipMemsetAsync(dstat, 0, 3 * 64 * 8, stream);
  k_fps<<<NB_TOTAL, FT, 0, stream>>>(xyz, newxyz, sqn, pts, ptst, w1, w1t, w2, w2t,
                                     te, ce, wt, bt, wc, bc, scl, shf);
  k_ballq<<<BB * SS / 4, 256, 0, stream>>>(xyz, sqn, newxyz, gi);
  k_mlp0<0><<<BB * SS, 256, 0, stream>>>(xyz, ptst, newxyz, gi, w0, b0, dstat, fmu, frs, g0, be0, xp);
  k_fin<<<1, 64, 0, stream>>>(dstat, fmu, frs, 1.0 / (16.0 * SS * KK));
  k_mlp0<1><<<BB * SS, 256, 0, stream>>>(xyz, ptst, newxyz, gi, w0, b0, dstat, fmu, frs, g0, be0, xp);
  k_mlp1<<<BB * SS / 8, 256, 0, stream>>>(xp, w1t, b1, h1, dstat + 64);
  k_fin<<<1, 64, 0, stream>>>(dstat + 64, fmu + 32, frs + 32, 1.0 / (64.0 * SS));
  k_mlp2<<<BB * SS / 8, 256, 0, stream>>>(h1, w2t, b2, fmu + 32, frs + 32, g1, be1, h2, dstat + 128);
  k_fin<<<1, 64, 0, stream>>>(dstat + 128, fmu + 64, frs + 64, 1.0 / (16.0 * SS));
  k_final<<<BB * 128 * SS / 256, 256, 0, stream>>>(h2, xp, fmu + 64, frs + 64, g2, be2, scl, shf, outnp);
}